// Round 5
// baseline (226.281 us; speedup 1.0000x reference)
//
#include <hip/hip_runtime.h>
#include <math.h>

#define NN 8192      // nodes
#define FH 128       // hidden
#define NC 16        // clusters
#define HP 132       // padded LDS row
#define CHUNK 32     // nodes per block in node phase
#define NBLK 256
#define NTHR 256

// ---------------- workspace layout (floats) ----------------
#define WS_CNT   0          // [8192]
#define WS_AGG4  8192       // [32768]
#define WS_ORAW  40960      // 4 x 2048 replicas
#define WS_SS    49152      // 4 x 256
#define WS_CA    50176      // 16 x 16
#define WS_CS    50432      // 16 x 16
#define WS_OADJ  50688      // 4 x 256
#define WS_BAR   51712      // [16] barrier counters (ints)
#define WS_ACC_FLOATS 51728

// ---------------- K0: zero accumulators + barrier state ----------------
__global__ __launch_bounds__(256) void k_zero(float4* __restrict__ ws) {
    int i = blockIdx.x * blockDim.x + threadIdx.x;
    if (i < WS_ACC_FLOATS / 4) ws[i] = make_float4(0.f, 0.f, 0.f, 0.f);
}

// ---------------- software grid barrier (all NBLK blocks co-resident) ----------------
__device__ __forceinline__ void gbar(int* bar) {
    __syncthreads();
    if (threadIdx.x == 0) {
        int g = __hip_atomic_load(&bar[1], __ATOMIC_RELAXED, __HIP_MEMORY_SCOPE_AGENT);
        __threadfence();   // make this block's prior writes visible
        int prev = __hip_atomic_fetch_add(&bar[0], 1, __ATOMIC_ACQ_REL,
                                          __HIP_MEMORY_SCOPE_AGENT);
        if (prev == NBLK - 1) {
            __hip_atomic_store(&bar[0], 0, __ATOMIC_RELAXED, __HIP_MEMORY_SCOPE_AGENT);
            __hip_atomic_fetch_add(&bar[1], 1, __ATOMIC_RELEASE,
                                   __HIP_MEMORY_SCOPE_AGENT);
        } else {
            while (__hip_atomic_load(&bar[1], __ATOMIC_ACQUIRE,
                                     __HIP_MEMORY_SCOPE_AGENT) == g)
                __builtin_amdgcn_s_sleep(1);
        }
        __threadfence();   // acquire: see all other blocks' writes
    }
    __syncthreads();
}

__device__ __forceinline__ float selu_f(float x) {
    const float a = 1.6732632423543772f, sc = 1.0507009873554805f;
    return sc * (x > 0.0f ? x : a * (expf(x) - 1.0f));
}

__device__ __forceinline__ float bsum256(float v, float* sh) {
    #pragma unroll
    for (int o = 32; o; o >>= 1) v += __shfl_down(v, o, 64);
    if ((threadIdx.x & 63) == 0) sh[threadIdx.x >> 6] = v;
    __syncthreads();
    float r = sh[0] + sh[1] + sh[2] + sh[3];
    __syncthreads();
    return r;
}
__device__ __forceinline__ float bmax256(float v, float* sh) {
    #pragma unroll
    for (int o = 32; o; o >>= 1) v = fmaxf(v, __shfl_down(v, o, 64));
    if ((threadIdx.x & 63) == 0) sh[threadIdx.x >> 6] = v;
    __syncthreads();
    float r = fmaxf(fmaxf(sh[0], sh[1]), fmaxf(sh[2], sh[3]));
    __syncthreads();
    return r;
}

__global__ __launch_bounds__(NTHR) void k_mega(
    const float* __restrict__ x, const float* __restrict__ W1,
    const float* __restrict__ b1, const float* __restrict__ Wp,
    const float* __restrict__ bp, const int* __restrict__ ei,
    float* __restrict__ ws, float* __restrict__ s_out,
    float* __restrict__ d_out, int E)
{
    float* cnt  = ws + WS_CNT;
    float* agg4 = ws + WS_AGG4;
    float* oraw = ws + WS_ORAW;
    float* ssb  = ws + WS_SS;
    float* cab  = ws + WS_CA;
    float* csb  = ws + WS_CS;
    float* oadj = ws + WS_OADJ;
    int*   bar  = (int*)(ws + WS_BAR);

    __shared__ float h_lds[CHUNK][HP];     // 16.9 KB
    __shared__ float wpT[NC * HP];         // 8.4 KB
    __shared__ float s_lds[CHUNK][NC];     // 2 KB
    __shared__ float z_lds[CHUNK][4];
    __shared__ float c_lds[CHUNK];
    __shared__ float red[16 * 16 * 16];    // 16 KB
    __shared__ float shred[4];

    int t = threadIdx.x;
    int b = blockIdx.x;
    int tid = b * NTHR + t;

    // ---------- Phase 1: in-degree counts (cnt zeroed by k_zero) ----------
    int e0 = tid * 2, e1 = tid * 2 + 1;
    bool v0 = e0 < E, v1 = e1 < E;
    int es0 = 0, ed0 = 0, es1 = 0, ed1 = 0;
    if (v0) { es0 = ei[e0]; ed0 = ei[E + e0]; }
    if (v1) { es1 = ei[e1]; ed1 = ei[E + e1]; }
    if (v0) atomicAdd(&cnt[ed0], 1.0f);
    if (v1) atomicAdd(&cnt[ed1], 1.0f);
    gbar(bar);

    // ---------- Phase 2: edge aggregation in 4-dim input space ----------
    if (v0) {
        float norm = rsqrtf(cnt[es0] + 1.0f) * rsqrtf(cnt[ed0] + 1.0f);
        float4 xv = reinterpret_cast<const float4*>(x)[es0];
        atomicAdd(&agg4[ed0 * 4 + 0], norm * xv.x);
        atomicAdd(&agg4[ed0 * 4 + 1], norm * xv.y);
        atomicAdd(&agg4[ed0 * 4 + 2], norm * xv.z);
        atomicAdd(&agg4[ed0 * 4 + 3], norm * xv.w);
    }
    if (v1) {
        float norm = rsqrtf(cnt[es1] + 1.0f) * rsqrtf(cnt[ed1] + 1.0f);
        float4 xv = reinterpret_cast<const float4*>(x)[es1];
        atomicAdd(&agg4[ed1 * 4 + 0], norm * xv.x);
        atomicAdd(&agg4[ed1 * 4 + 1], norm * xv.y);
        atomicAdd(&agg4[ed1 * 4 + 2], norm * xv.z);
        atomicAdd(&agg4[ed1 * 4 + 3], norm * xv.w);
    }
    gbar(bar);

    // ---------- Phase 3: fused node pipeline (32 nodes per block) ----------
    {
        int base = b * CHUNK;
        #pragma unroll
        for (int r = 0; r < 8; ++r) {
            int idx = r * 256 + t;             // = f*16 + c
            wpT[(idx & 15) * HP + (idx >> 4)] = Wp[idx];
        }
        if (t < CHUNK) {
            float4 a  = reinterpret_cast<const float4*>(agg4)[base + t];
            float4 xv = reinterpret_cast<const float4*>(x)[base + t];
            float cn = cnt[base + t];
            c_lds[t] = cn;
            float di = 1.0f / (cn + 1.0f);
            z_lds[t][0] = a.x + xv.x * di;
            z_lds[t][1] = a.y + xv.y * di;
            z_lds[t][2] = a.z + xv.z * di;
            z_lds[t][3] = a.w + xv.w * di;
        }
        __syncthreads();

        int f = t & 127;
        {
            float w0 = W1[f], w1 = W1[128 + f], w2 = W1[256 + f], w3 = W1[384 + f];
            float bb = b1[f];
            int n0 = t >> 7;
            #pragma unroll
            for (int r = 0; r < 16; ++r) {
                int n = n0 + r * 2;
                float v = fmaf(z_lds[n][0], w0, bb);
                v = fmaf(z_lds[n][1], w1, v);
                v = fmaf(z_lds[n][2], w2, v);
                v = fmaf(z_lds[n][3], w3, v);
                h_lds[n][f] = fmaxf(v, 0.0f);
            }
        }
        __syncthreads();

        int c = t & 15, g = t >> 4;
        const float4* wrow = reinterpret_cast<const float4*>(&wpT[c * HP]);
        #pragma unroll
        for (int pass = 0; pass < 2; ++pass) {
            int n = pass * 16 + g;
            const float4* hrow = reinterpret_cast<const float4*>(&h_lds[n][0]);
            float logit = bp[c];
            #pragma unroll 8
            for (int q = 0; q < 32; ++q) {
                float4 hv = hrow[q];
                float4 wv = wrow[q];
                logit = fmaf(hv.x, wv.x, logit);
                logit = fmaf(hv.y, wv.y, logit);
                logit = fmaf(hv.z, wv.z, logit);
                logit = fmaf(hv.w, wv.w, logit);
            }
            float m = logit;
            #pragma unroll
            for (int o = 8; o; o >>= 1) m = fmaxf(m, __shfl_xor(m, o, 16));
            float ex = expf(logit - m);
            float sum = ex;
            #pragma unroll
            for (int o = 8; o; o >>= 1) sum += __shfl_xor(sum, o, 16);
            float sv = ex / sum;
            s_lds[n][c] = sv;
            s_out[(base + n) * NC + c] = sv;
        }
        __syncthreads();

        float acc[8] = {0, 0, 0, 0, 0, 0, 0, 0};
        float acc_ss = 0.0f, acc_ca = 0.0f, acc_cs = 0.0f;
        int ch = t >> 7;
        int cS = t >> 4, kS = t & 15;
        #pragma unroll
        for (int i = 0; i < CHUNK; ++i) {
            float hv = h_lds[i][f];
            const float4* sv = reinterpret_cast<const float4*>(&s_lds[i][0]);
            float4 sa = sv[ch * 2], sb = sv[ch * 2 + 1];
            acc[0] = fmaf(sa.x, hv, acc[0]);
            acc[1] = fmaf(sa.y, hv, acc[1]);
            acc[2] = fmaf(sa.z, hv, acc[2]);
            acc[3] = fmaf(sa.w, hv, acc[3]);
            acc[4] = fmaf(sb.x, hv, acc[4]);
            acc[5] = fmaf(sb.y, hv, acc[5]);
            acc[6] = fmaf(sb.z, hv, acc[6]);
            acc[7] = fmaf(sb.w, hv, acc[7]);
            acc_ss = fmaf(s_lds[i][cS], s_lds[i][kS], acc_ss);
        }
        if (t < NC) {
            #pragma unroll
            for (int i = 0; i < CHUNK; ++i) {
                acc_ca = fmaf(s_lds[i][t], c_lds[i], acc_ca);
                acc_cs += s_lds[i][t];
            }
        }
        int rep = b & 3;
        #pragma unroll
        for (int j = 0; j < 8; ++j)
            atomicAdd(&oraw[rep * 2048 + (ch * 8 + j) * FH + f], acc[j]);
        atomicAdd(&ssb[rep * 256 + cS * NC + kS], acc_ss);
        if (t < NC) {
            int rep16 = b & 15;
            atomicAdd(&cab[rep16 * NC + t], acc_ca);
            atomicAdd(&csb[rep16 * NC + t], acc_cs);
        }
    }
    gbar(bar);

    // ---------- Phase 4: out_adj[k][c] = sum_e s[src,k]*s[dst,c] ----------
    {
        int c = t & 15;
        int grp  = tid >> 4;
        int ngrp = (NBLK * NTHR) >> 4;     // 4096
        float acc[16];
        #pragma unroll
        for (int k = 0; k < 16; ++k) acc[k] = 0.0f;
        for (int e = grp; e < E; e += ngrp) {
            int sN = ei[e], dN = ei[E + e];
            float a = s_out[sN * NC + c];
            float bb = s_out[dN * NC + c];
            #pragma unroll
            for (int k = 0; k < 16; ++k)
                acc[k] = fmaf(__shfl(a, k, 16), bb, acc[k]);
        }
        int gl = t >> 4;
        #pragma unroll
        for (int k = 0; k < 16; ++k) red[gl * 256 + k * 16 + c] = acc[k];
        __syncthreads();
        int kk = t >> 4, cc = t & 15;
        float v = 0.0f;
        #pragma unroll
        for (int g2 = 0; g2 < 16; ++g2) v += red[g2 * 256 + kk * 16 + cc];
        atomicAdd(&oadj[(b & 3) * 256 + kk * 16 + cc], v);
    }
    gbar(bar);

    // ---------- Phase 5: losses + selu + log_softmax (block 0 only) ----------
    if (b == 0) {
        float Ef = (float)E;
        float s0 = 0.0f, s1 = 0.0f;
        if (t < 128) {
            #pragma unroll
            for (int r = 0; r < 4; ++r) {
                s0 += ssb[r * 256 + t];
                s1 += ssb[r * 256 + 128 + t];
            }
        }
        float fro = sqrtf(bsum256(s0 * s0 + s1 * s1, shred));
        float d0 = 0.0f, d1 = 0.0f;
        if (t < 128) {
            d0 = s0 / fro - ((t % 17 == 0) ? 0.25f : 0.0f);
            d1 = s1 / fro - (((t + 128) % 17 == 0) ? 0.25f : 0.0f);
        }
        float ortho = sqrtf(bsum256(d0 * d0 + d1 * d1, shred));
        float tv = 0.0f, ca = 0.0f, cs = 0.0f;
        if (t < NC) {
            #pragma unroll
            for (int r = 0; r < 4; ++r) tv += oadj[r * 256 + t * 17];
            #pragma unroll
            for (int r = 0; r < 16; ++r) { ca += cab[r * NC + t]; cs += csb[r * NC + t]; }
        }
        float tr_adj = bsum256(tv, shred);
        float tr_n = bsum256(ca * ca, shred) / Ef;
        float spectral = -(tr_adj - tr_n) / Ef;
        float cluster = sqrtf(bsum256(cs * cs, shred)) / (float)NN * 4.0f - 1.0f;
        if (t == 0) d_out[NC * FH] = spectral + ortho + cluster;
        for (int cR = 0; cR < NC; ++cR) {
            float v = 0.0f;
            if (t < 128) {
                #pragma unroll
                for (int r = 0; r < 4; ++r) v += oraw[r * 2048 + cR * FH + t];
                v = selu_f(v);
            }
            float mx = bmax256(t < 128 ? v : -1e30f, shred);
            float e = (t < 128) ? expf(v - mx) : 0.0f;
            float sm = bsum256(e, shred);
            if (t < 128) d_out[cR * FH + t] = v - mx - logf(sm);
        }
    }
}

extern "C" void kernel_launch(void* const* d_in, const int* in_sizes, int n_in,
                              void* d_out, int out_size, void* d_ws, size_t ws_size,
                              hipStream_t stream) {
    const float* x  = (const float*)d_in[0];
    const float* W1 = (const float*)d_in[1];
    const float* b1 = (const float*)d_in[2];
    const float* Wp = (const float*)d_in[3];
    const float* bp = (const float*)d_in[4];
    const int*   ei = (const int*)d_in[5];
    int E = in_sizes[5] / 2;

    float* ws  = (float*)d_ws;
    float* out = (float*)d_out;           // [0..2047] log_softmax, [2048] loss
    float* s   = out + NC * FH + 1;       // [2049..] assignments (8192 x 16)

    k_zero<<<(WS_ACC_FLOATS / 4 + 255) / 256, 256, 0, stream>>>((float4*)d_ws);
    k_mega<<<NBLK, NTHR, 0, stream>>>(x, W1, b1, Wp, bp, ei, ws, s, out, E);
}

// Round 6
// 110.068 us; speedup vs baseline: 2.0558x; 2.0558x over previous
//
#include <hip/hip_runtime.h>
#include <math.h>

#define NN 8192      // nodes
#define FH 128       // hidden
#define NC 16        // clusters
#define HP 132       // padded LDS row
#define CHUNK 32     // nodes per block in node phase
#define NBLK 256
#define NTHR 256

// ---------------- workspace layout (floats) ----------------
#define WS_CNT   0          // [8192]
#define WS_AGG4  8192       // [32768]
#define WS_ORAW  40960      // 4 x 2048 replicas
#define WS_SS    49152      // 4 x 256
#define WS_CA    50176      // 16 x 16
#define WS_CS    50432      // 16 x 16
#define WS_OADJ  50688      // 4 x 256
#define WS_BAR   51712      // [128] ints: [0]=arrivals, [64]=generation, [96]=done
#define WS_ACC_FLOATS 51840 // /4 = 12960 float4

#define BAR_ARRIVE 0
#define BAR_GEN    64
#define BAR_DONE   96

// ---------------- K0: zero accumulators + barrier state ----------------
__global__ __launch_bounds__(256) void k_zero(float4* __restrict__ ws) {
    int i = blockIdx.x * blockDim.x + threadIdx.x;
    if (i < WS_ACC_FLOATS / 4) ws[i] = make_float4(0.f, 0.f, 0.f, 0.f);
}

// ---- software grid barrier: relaxed spin, fences only at entry/exit ----
__device__ __forceinline__ void gbar(int* bar) {
    __syncthreads();                       // all block's vmem drained at barrier
    if (threadIdx.x == 0) {
        __threadfence();                   // release this block's writes
        int g = __hip_atomic_load(&bar[BAR_GEN], __ATOMIC_RELAXED,
                                  __HIP_MEMORY_SCOPE_AGENT);
        int prev = __hip_atomic_fetch_add(&bar[BAR_ARRIVE], 1, __ATOMIC_RELAXED,
                                          __HIP_MEMORY_SCOPE_AGENT);
        if (prev == NBLK - 1) {
            __hip_atomic_store(&bar[BAR_ARRIVE], 0, __ATOMIC_RELAXED,
                               __HIP_MEMORY_SCOPE_AGENT);
            __threadfence();               // order arrivals -> gen flip
            __hip_atomic_fetch_add(&bar[BAR_GEN], 1, __ATOMIC_RELAXED,
                                   __HIP_MEMORY_SCOPE_AGENT);
        } else {
            while (__hip_atomic_load(&bar[BAR_GEN], __ATOMIC_RELAXED,
                                     __HIP_MEMORY_SCOPE_AGENT) == g)
                __builtin_amdgcn_s_sleep(2);
        }
        __threadfence();                   // acquire other blocks' writes
    }
    __syncthreads();
}

__device__ __forceinline__ float selu_f(float x) {
    const float a = 1.6732632423543772f, sc = 1.0507009873554805f;
    return sc * (x > 0.0f ? x : a * (expf(x) - 1.0f));
}

__device__ __forceinline__ float bsum256(float v, float* sh) {
    #pragma unroll
    for (int o = 32; o; o >>= 1) v += __shfl_down(v, o, 64);
    if ((threadIdx.x & 63) == 0) sh[threadIdx.x >> 6] = v;
    __syncthreads();
    float r = sh[0] + sh[1] + sh[2] + sh[3];
    __syncthreads();
    return r;
}
__device__ __forceinline__ float bmax256(float v, float* sh) {
    #pragma unroll
    for (int o = 32; o; o >>= 1) v = fmaxf(v, __shfl_down(v, o, 64));
    if ((threadIdx.x & 63) == 0) sh[threadIdx.x >> 6] = v;
    __syncthreads();
    float r = fmaxf(fmaxf(sh[0], sh[1]), fmaxf(sh[2], sh[3]));
    __syncthreads();
    return r;
}

__global__ __launch_bounds__(NTHR) void k_mega(
    const float* __restrict__ x, const float* __restrict__ W1,
    const float* __restrict__ b1, const float* __restrict__ Wp,
    const float* __restrict__ bp, const int* __restrict__ ei,
    float* __restrict__ ws, float* __restrict__ s_out,
    float* __restrict__ d_out, int E)
{
    float* cnt  = ws + WS_CNT;
    float* agg4 = ws + WS_AGG4;
    float* oraw = ws + WS_ORAW;
    float* ssb  = ws + WS_SS;
    float* cab  = ws + WS_CA;
    float* csb  = ws + WS_CS;
    float* oadj = ws + WS_OADJ;
    int*   bar  = (int*)(ws + WS_BAR);

    __shared__ float h_lds[CHUNK][HP];     // 16.9 KB
    __shared__ float wpT[NC * HP];         // 8.4 KB
    __shared__ float s_lds[CHUNK][NC];     // 2 KB
    __shared__ float z_lds[CHUNK][4];
    __shared__ float c_lds[CHUNK];
    __shared__ float red[16 * 16 * 16];    // 16 KB
    __shared__ float shred[4];
    __shared__ int lastflag;

    int t = threadIdx.x;
    int b = blockIdx.x;
    int tid = b * NTHR + t;

    // ---------- Phase 1: in-degree counts (cnt zeroed by k_zero) ----------
    int e0 = tid * 2;
    bool v0 = e0 < E, v1 = (e0 + 1) < E;
    int2 es = v1 ? *reinterpret_cast<const int2*>(&ei[e0])
                 : make_int2(v0 ? ei[e0] : 0, 0);
    int2 ed = v1 ? *reinterpret_cast<const int2*>(&ei[E + e0])
                 : make_int2(v0 ? ei[E + e0] : 0, 0);
    if (v0) atomicAdd(&cnt[ed.x], 1.0f);
    if (v1) atomicAdd(&cnt[ed.y], 1.0f);
    gbar(bar);

    // ---------- Phase 2: agg4[d] += x[s] * dinv[s]  (dinv[d] deferred) ----------
    if (v0) {
        float di = rsqrtf(cnt[es.x] + 1.0f);
        float4 xv = reinterpret_cast<const float4*>(x)[es.x];
        atomicAdd(&agg4[ed.x * 4 + 0], di * xv.x);
        atomicAdd(&agg4[ed.x * 4 + 1], di * xv.y);
        atomicAdd(&agg4[ed.x * 4 + 2], di * xv.z);
        atomicAdd(&agg4[ed.x * 4 + 3], di * xv.w);
    }
    if (v1) {
        float di = rsqrtf(cnt[es.y] + 1.0f);
        float4 xv = reinterpret_cast<const float4*>(x)[es.y];
        atomicAdd(&agg4[ed.y * 4 + 0], di * xv.x);
        atomicAdd(&agg4[ed.y * 4 + 1], di * xv.y);
        atomicAdd(&agg4[ed.y * 4 + 2], di * xv.z);
        atomicAdd(&agg4[ed.y * 4 + 3], di * xv.w);
    }
    gbar(bar);

    // ---------- Phase 3: fused node pipeline (32 nodes per block) ----------
    {
        int base = b * CHUNK;
        #pragma unroll
        for (int r = 0; r < 8; ++r) {
            int idx = r * 256 + t;             // = f*16 + c
            wpT[(idx & 15) * HP + (idx >> 4)] = Wp[idx];
        }
        if (t < CHUNK) {
            float4 a  = reinterpret_cast<const float4*>(agg4)[base + t];
            float4 xv = reinterpret_cast<const float4*>(x)[base + t];
            float cn = cnt[base + t];
            c_lds[t] = cn;
            float di = rsqrtf(cn + 1.0f);
            // z = dinv * (agg4 + x * dinv)
            z_lds[t][0] = di * fmaf(xv.x, di, a.x);
            z_lds[t][1] = di * fmaf(xv.y, di, a.y);
            z_lds[t][2] = di * fmaf(xv.z, di, a.z);
            z_lds[t][3] = di * fmaf(xv.w, di, a.w);
        }
        __syncthreads();

        int f = t & 127;
        {
            float w0 = W1[f], w1 = W1[128 + f], w2 = W1[256 + f], w3 = W1[384 + f];
            float bb = b1[f];
            int n0 = t >> 7;
            #pragma unroll
            for (int r = 0; r < 16; ++r) {
                int n = n0 + r * 2;
                float v = fmaf(z_lds[n][0], w0, bb);
                v = fmaf(z_lds[n][1], w1, v);
                v = fmaf(z_lds[n][2], w2, v);
                v = fmaf(z_lds[n][3], w3, v);
                h_lds[n][f] = fmaxf(v, 0.0f);
            }
        }
        __syncthreads();

        int c = t & 15, g = t >> 4;
        const float4* wrow = reinterpret_cast<const float4*>(&wpT[c * HP]);
        #pragma unroll
        for (int pass = 0; pass < 2; ++pass) {
            int n = pass * 16 + g;
            const float4* hrow = reinterpret_cast<const float4*>(&h_lds[n][0]);
            float logit = bp[c];
            #pragma unroll 8
            for (int q = 0; q < 32; ++q) {
                float4 hv = hrow[q];
                float4 wv = wrow[q];
                logit = fmaf(hv.x, wv.x, logit);
                logit = fmaf(hv.y, wv.y, logit);
                logit = fmaf(hv.z, wv.z, logit);
                logit = fmaf(hv.w, wv.w, logit);
            }
            float m = logit;
            #pragma unroll
            for (int o = 8; o; o >>= 1) m = fmaxf(m, __shfl_xor(m, o, 16));
            float ex = expf(logit - m);
            float sum = ex;
            #pragma unroll
            for (int o = 8; o; o >>= 1) sum += __shfl_xor(sum, o, 16);
            float sv = ex / sum;
            s_lds[n][c] = sv;
            s_out[(base + n) * NC + c] = sv;
        }
        __syncthreads();

        float acc[8] = {0, 0, 0, 0, 0, 0, 0, 0};
        float acc_ss = 0.0f, acc_ca = 0.0f, acc_cs = 0.0f;
        int ch = t >> 7;
        int cS = t >> 4, kS = t & 15;
        #pragma unroll
        for (int i = 0; i < CHUNK; ++i) {
            float hv = h_lds[i][f];
            const float4* sv = reinterpret_cast<const float4*>(&s_lds[i][0]);
            float4 sa = sv[ch * 2], sb = sv[ch * 2 + 1];
            acc[0] = fmaf(sa.x, hv, acc[0]);
            acc[1] = fmaf(sa.y, hv, acc[1]);
            acc[2] = fmaf(sa.z, hv, acc[2]);
            acc[3] = fmaf(sa.w, hv, acc[3]);
            acc[4] = fmaf(sb.x, hv, acc[4]);
            acc[5] = fmaf(sb.y, hv, acc[5]);
            acc[6] = fmaf(sb.z, hv, acc[6]);
            acc[7] = fmaf(sb.w, hv, acc[7]);
            acc_ss = fmaf(s_lds[i][cS], s_lds[i][kS], acc_ss);
        }
        if (t < NC) {
            #pragma unroll
            for (int i = 0; i < CHUNK; ++i) {
                acc_ca = fmaf(s_lds[i][t], c_lds[i], acc_ca);
                acc_cs += s_lds[i][t];
            }
        }
        int rep = b & 3;
        #pragma unroll
        for (int j = 0; j < 8; ++j)
            atomicAdd(&oraw[rep * 2048 + (ch * 8 + j) * FH + f], acc[j]);
        atomicAdd(&ssb[rep * 256 + cS * NC + kS], acc_ss);
        if (t < NC) {
            int rep16 = b & 15;
            atomicAdd(&cab[rep16 * NC + t], acc_ca);
            atomicAdd(&csb[rep16 * NC + t], acc_cs);
        }
    }
    gbar(bar);

    // ---------- Phase 4: out_adj[k][c] = sum_e s[src,k]*s[dst,c] ----------
    {
        int c = t & 15;
        int grp  = tid >> 4;
        int ngrp = (NBLK * NTHR) >> 4;     // 4096
        float acc[16];
        #pragma unroll
        for (int k = 0; k < 16; ++k) acc[k] = 0.0f;
        for (int e = grp; e < E; e += ngrp) {
            int sN = ei[e], dN = ei[E + e];
            float a = s_out[sN * NC + c];
            float bb = s_out[dN * NC + c];
            #pragma unroll
            for (int k = 0; k < 16; ++k)
                acc[k] = fmaf(__shfl(a, k, 16), bb, acc[k]);
        }
        int gl = t >> 4;
        #pragma unroll
        for (int k = 0; k < 16; ++k) red[gl * 256 + k * 16 + c] = acc[k];
        __syncthreads();
        int kk = t >> 4, cc = t & 15;
        float v = 0.0f;
        #pragma unroll
        for (int g2 = 0; g2 < 16; ++g2) v += red[g2 * 256 + kk * 16 + cc];
        atomicAdd(&oadj[(b & 3) * 256 + kk * 16 + cc], v);
    }

    // ---------- last-done block runs the epilogue ----------
    __syncthreads();                       // drain this block's oadj atomics
    if (t == 0) {
        __threadfence();
        int prev = __hip_atomic_fetch_add(&bar[BAR_DONE], 1, __ATOMIC_RELAXED,
                                          __HIP_MEMORY_SCOPE_AGENT);
        lastflag = (prev == NBLK - 1) ? 1 : 0;
        if (lastflag) __threadfence();     // acquire all blocks' accumulators
    }
    __syncthreads();
    if (!lastflag) return;

    // ---------- Phase 5: losses + selu + log_softmax ----------
    {
        float Ef = (float)E;
        float s0 = 0.0f, s1 = 0.0f;
        if (t < 128) {
            #pragma unroll
            for (int r = 0; r < 4; ++r) {
                s0 += ssb[r * 256 + t];
                s1 += ssb[r * 256 + 128 + t];
            }
        }
        float fro = sqrtf(bsum256(s0 * s0 + s1 * s1, shred));
        float d0 = 0.0f, d1 = 0.0f;
        if (t < 128) {
            d0 = s0 / fro - ((t % 17 == 0) ? 0.25f : 0.0f);
            d1 = s1 / fro - (((t + 128) % 17 == 0) ? 0.25f : 0.0f);
        }
        float ortho = sqrtf(bsum256(d0 * d0 + d1 * d1, shred));
        float tv = 0.0f, ca = 0.0f, cs = 0.0f;
        if (t < NC) {
            #pragma unroll
            for (int r = 0; r < 4; ++r) tv += oadj[r * 256 + t * 17];
            #pragma unroll
            for (int r = 0; r < 16; ++r) { ca += cab[r * NC + t]; cs += csb[r * NC + t]; }
        }
        float tr_adj = bsum256(tv, shred);
        float tr_n = bsum256(ca * ca, shred) / Ef;
        float spectral = -(tr_adj - tr_n) / Ef;
        float cluster = sqrtf(bsum256(cs * cs, shred)) / (float)NN * 4.0f - 1.0f;
        if (t == 0) d_out[NC * FH] = spectral + ortho + cluster;
        for (int cR = 0; cR < NC; ++cR) {
            float v = 0.0f;
            if (t < 128) {
                #pragma unroll
                for (int r = 0; r < 4; ++r) v += oraw[r * 2048 + cR * FH + t];
                v = selu_f(v);
            }
            float mx = bmax256(t < 128 ? v : -1e30f, shred);
            float e = (t < 128) ? expf(v - mx) : 0.0f;
            float sm = bsum256(e, shred);
            if (t < 128) d_out[cR * FH + t] = v - mx - logf(sm);
        }
    }
}

extern "C" void kernel_launch(void* const* d_in, const int* in_sizes, int n_in,
                              void* d_out, int out_size, void* d_ws, size_t ws_size,
                              hipStream_t stream) {
    const float* x  = (const float*)d_in[0];
    const float* W1 = (const float*)d_in[1];
    const float* b1 = (const float*)d_in[2];
    const float* Wp = (const float*)d_in[3];
    const float* bp = (const float*)d_in[4];
    const int*   ei = (const int*)d_in[5];
    int E = in_sizes[5] / 2;

    float* ws  = (float*)d_ws;
    float* out = (float*)d_out;           // [0..2047] log_softmax, [2048] loss
    float* s   = out + NC * FH + 1;       // [2049..] assignments (8192 x 16)

    k_zero<<<(WS_ACC_FLOATS / 4 + 255) / 256, 256, 0, stream>>>((float4*)d_ws);
    k_mega<<<NBLK, NTHR, 0, stream>>>(x, W1, b1, Wp, bp, ei, ws, s, out, E);
}